// Round 5
// baseline (19124.724 us; speedup 1.0000x reference)
//
#include <hip/hip_runtime.h>
#include <stdint.h>

// Seq2Seq (bi-LSTM encoder + greedy LSTM decoder), MI355X gfx950.
// v5: spill-free classifier under the 64-VGPR budget.
//   R4 post-mortem: amdgpu_waves_per_eu(4,4) was ignored (VGPR stayed 64,
//   spill traffic identical). Give up on raising the budget; restructure so
//   the classifier's live set fits 64 VGPRs: lane=(kc[0,4) x bg[0,16)),
//   wave owns 8 rows, acc[8][2]=16 regs, h b128 shared across 8 rows
//   (LDS ~10us/step), w loads coalesced 64B/row-instr with 4 in flight,
//   butterfly over kc + static row-select tree.
//
// B=32 S=128 T=64 V=32000 E=512 H=512 (4H=2048 gates per cell)

#define NT 1024
#define NBLK 256

constexpr int HSTR = 580;    // enc h-stage LDS row stride (512 + pad, %32==4)
constexpr int XSTR = 1156;   // dec [x|h]-stage stride (1024 + pad, %32==4)
constexpr unsigned LDS_BYTES = 150528;

// workspace layout (bytes)
constexpr size_t OFF_AMAX  = 0;                     // 63*32 u64 = 16128
constexpr size_t OFF_FLAGS = 16128;                 // 256 u32  = 1024
constexpr size_t OFF_XG    = 17408;                 // 256*128*32*16 f32 = 67108864
constexpr size_t OFF_HENC  = OFF_XG + 67108864ULL;  // 2buf*2dir*32*512 f32 = 262144
constexpr size_t OFF_HCAT  = OFF_HENC + 262144ULL;  // 2buf*32*1024 f32 = 262144

__device__ __forceinline__ float sigm(float x) {
  if (x >= 0.f) return 1.f / (1.f + expf(-x));
  float e = expf(x);
  return e / (1.f + e);
}

__device__ __forceinline__ void fma4(const float4& w, const float4& h, float4& a) {
  a.x = fmaf(w.x, h.x, a.x);
  a.y = fmaf(w.y, h.y, a.y);
  a.z = fmaf(w.z, h.z, a.z);
  a.w = fmaf(w.w, h.w, a.w);
}

__device__ __forceinline__ float hsum4(const float4& a) {
  return (a.x + a.y) + (a.z + a.w);
}

__device__ __forceinline__ float dot4(const float4& w, const float4& h, float acc) {
  return fmaf(w.x, h.x, fmaf(w.y, h.y, fmaf(w.z, h.z, fmaf(w.w, h.w, acc))));
}

__device__ __forceinline__ unsigned long long lgkey(float lg, int vr) {
  unsigned u = __float_as_uint(lg);
  u = (u & 0x80000000u) ? ~u : (u | 0x80000000u);
  return ((unsigned long long)u << 32) | (0xFFFFFFFFu - (unsigned)vr);
}

// device-scope flag barrier: 256 blocks, thread t<256 polls flags[t].
__device__ __forceinline__ void gbar(unsigned* flags, unsigned gen) {
  __syncthreads();
  if (threadIdx.x == 0) {
    __threadfence();
    __hip_atomic_store(&flags[blockIdx.x], gen, __ATOMIC_RELEASE,
                       __HIP_MEMORY_SCOPE_AGENT);
  }
  if (threadIdx.x < NBLK) {
    while (__hip_atomic_load(&flags[threadIdx.x], __ATOMIC_ACQUIRE,
                             __HIP_MEMORY_SCOPE_AGENT) < gen) {
      __builtin_amdgcn_s_sleep(2);
    }
  }
  __syncthreads();
}

__global__ __launch_bounds__(NT, 4) void s2s_kernel(
    const int* __restrict__ src, const int* __restrict__ tgt,
    const float* __restrict__ enc_emb, const float* __restrict__ dec_emb,
    const float* __restrict__ ewih_f, const float* __restrict__ ewhh_f,
    const float* __restrict__ ebih_f, const float* __restrict__ ebhh_f,
    const float* __restrict__ ewih_r, const float* __restrict__ ewhh_r,
    const float* __restrict__ ebih_r, const float* __restrict__ ebhh_r,
    const float* __restrict__ dwih_f, const float* __restrict__ dwhh_f,
    const float* __restrict__ dbih_f, const float* __restrict__ dbhh_f,
    const float* __restrict__ dwih_r, const float* __restrict__ dwhh_r,
    const float* __restrict__ dbih_r, const float* __restrict__ dbhh_r,
    const float* __restrict__ cls_w, const float* __restrict__ cls_b,
    float* __restrict__ out,
    unsigned long long* __restrict__ amax, unsigned* __restrict__ flags,
    float* __restrict__ Xg, float* __restrict__ h_enc, float* __restrict__ hcat) {
  extern __shared__ float smem[];
  const int tid = threadIdx.x;
  const int bid = blockIdx.x;
  const int d  = bid >> 7;          // 0 = forward, 1 = reverse
  const int u0 = (bid & 127) << 2;  // first of 4 owned LSTM units

  // LDS views per phase (aliased)
  float* hL  = smem;                      // enc: [32][HSTR]
  float* XgL = smem + 32 * HSTR;          // enc: [32*16]
  float* gL  = XgL + 512;                 // enc: [32*16]
  float* xhL = smem;                      // dec cell: [32][XSTR]
  float* gLd = smem + 32 * XSTR;          // dec cell: [32*16]  (floats 36992..37504)
  // classifier phase: cH float4[8192] at floats 0..32768 (128 KB)
  //                   oL [32][130] at floats 32768..36928
  //                   amaxL u64[32] at floats 37504..37568
  float* oL = smem + 32768;
  unsigned long long* amaxL = (unsigned long long*)(smem + 37504);

  // mapping E (phase0 + encoder scan): 2 rows x 4 b per thread, k-split 16
  const int rgE = tid >> 7;               // [0,8)
  const int bpE = (tid >> 4) & 7;         // [0,8)
  const int ksE = tid & 15;               // [0,16)
  const int r0E = rgE * 2, r1E = r0E + 1;
  const int growE0 = (r0E & 3) * 512 + u0 + (r0E >> 2);
  const int growE1 = (r1E & 3) * 512 + u0 + (r1E >> 2);
  // mapping D (decoder cells): 2 rows x 8 b per thread, k-split 32 over K=1024
  const int rgD = tid >> 7;
  const int bpD = (tid >> 5) & 3;         // [0,4)
  const int ksD = tid & 31;               // [0,32)
  const int r0D = rgD * 2, r1D = r0D + 1;
  const int growD0 = (r0D & 3) * 512 + u0 + (r0D >> 2);
  const int growD1 = (r1D & 3) * 512 + u0 + (r1D >> 2);

  const float* ewih = d ? ewih_r : ewih_f;
  const float* ewhh = d ? ewhh_r : ewhh_f;
  const float* ebih = d ? ebih_r : ebih_f;
  const float* ebhh = d ? ebhh_r : ebhh_f;
  const float* dwih = d ? dwih_r : dwih_f;
  const float* dwhh = d ? dwhh_r : dwhh_f;
  const float* dbih = d ? dbih_r : dbih_f;
  const float* dbhh = d ? dbhh_r : dbhh_f;

  float4 wA[8], wB[8];
  float biasA, biasB;
  float c_reg = 0.f;   // cell state for threads tid<128 (b=tid&31, j=tid>>5)
  unsigned gen = 0;

  // ---------------- phase 0: Xg = emb(src) @ wih^T + bih + bhh ----------------
#pragma unroll
  for (int i4 = 0; i4 < 8; ++i4) {
    wA[i4] = *(const float4*)(ewih + (size_t)growE0 * 512 + ksE * 32 + i4 * 4);
    wB[i4] = *(const float4*)(ewih + (size_t)growE1 * 512 + ksE * 32 + i4 * 4);
  }
  biasA = ebih[growE0] + ebhh[growE0];
  biasB = ebih[growE1] + ebhh[growE1];

  for (int t = 0; t < 128; ++t) {
    {  // stage x = enc_emb[src[b][t]] into hL
      int b = tid >> 5, i = tid & 31;
      int tok = src[b * 128 + t];
      const float* row = enc_emb + (size_t)tok * 512;
#pragma unroll
      for (int q = 0; q < 4; ++q) {
        int k = (i + 32 * q) * 4;
        float4 v = *(const float4*)(row + k);
        int pc = k + ((k >> 5) << 2);
        *(float4*)(hL + b * HSTR + pc) = v;
      }
    }
    __syncthreads();
    for (int gi = 0; gi < 4; ++gi) {
      int b = bpE * 4 + gi;
      const float* hb = hL + b * HSTR + ksE * 36;
      float4 a0 = {0, 0, 0, 0}, a1 = {0, 0, 0, 0};
#pragma unroll
      for (int i4 = 0; i4 < 8; ++i4) {
        float4 h4 = *(const float4*)(hb + i4 * 4);
        fma4(wA[i4], h4, a0);
        fma4(wB[i4], h4, a1);
      }
      float s0 = hsum4(a0), s1 = hsum4(a1);
#pragma unroll
      for (int m = 1; m <= 8; m <<= 1) {
        s0 += __shfl_xor(s0, m, 64);
        s1 += __shfl_xor(s1, m, 64);
      }
      if (ksE == 0) {
        float* xgp = Xg + ((size_t)bid << 16) + t * 512 + b * 16;
        xgp[r0E] = s0 + biasA;
        xgp[r1E] = s1 + biasB;
      }
    }
    __syncthreads();
  }

  // init h_enc[buf0] = 0 for owned units; zero out[:,0,:] slice
  if (tid < 128) {
    int b = tid & 31, j = tid >> 5;
    h_enc[((0 * 2 + d) * 32 + b) * 512 + u0 + j] = 0.f;
  }
  for (int i = tid; i < 4000; i += NT) {
    int b = i & 31, vv = i >> 5;  // vv < 125
    out[(size_t)b * 64 * 32000 + bid * 125 + vv] = 0.f;
  }
  gbar(flags, ++gen);

  // ---------------- encoder scan: 128 steps ----------------
#pragma unroll
  for (int i4 = 0; i4 < 8; ++i4) {
    wA[i4] = *(const float4*)(ewhh + (size_t)growE0 * 512 + ksE * 32 + i4 * 4);
    wB[i4] = *(const float4*)(ewhh + (size_t)growE1 * 512 + ksE * 32 + i4 * 4);
  }
  int cur = 0;
  for (int s = 0; s < 128; ++s) {
    const int td = d ? (127 - s) : s;
    {  // stage h_enc[cur][d] -> hL; stage this block's Xg slice -> XgL
      int b = tid >> 5, i = tid & 31;
      const float* hr = h_enc + ((size_t)(cur * 2 + d) * 32 + b) * 512;
#pragma unroll
      for (int q = 0; q < 4; ++q) {
        int k = (i + 32 * q) * 4;
        float4 v = *(const float4*)(hr + k);
        int pc = k + ((k >> 5) << 2);
        *(float4*)(hL + b * HSTR + pc) = v;
      }
      if (tid < 128) {
        ((float4*)XgL)[tid] =
            *(const float4*)(Xg + ((size_t)bid << 16) + td * 512 + tid * 4);
      }
    }
    __syncthreads();
    for (int gi = 0; gi < 4; ++gi) {
      int b = bpE * 4 + gi;
      const float* hb = hL + b * HSTR + ksE * 36;
      float4 a0 = {0, 0, 0, 0}, a1 = {0, 0, 0, 0};
#pragma unroll
      for (int i4 = 0; i4 < 8; ++i4) {
        float4 h4 = *(const float4*)(hb + i4 * 4);
        fma4(wA[i4], h4, a0);
        fma4(wB[i4], h4, a1);
      }
      float s0 = hsum4(a0), s1 = hsum4(a1);
#pragma unroll
      for (int m = 1; m <= 8; m <<= 1) {
        s0 += __shfl_xor(s0, m, 64);
        s1 += __shfl_xor(s1, m, 64);
      }
      if (ksE == 0) {
        gL[b * 16 + r0E] = s0 + XgL[b * 16 + r0E];
        gL[b * 16 + r1E] = s1 + XgL[b * 16 + r1E];
      }
    }
    __syncthreads();
    if (tid < 128) {
      int b = tid & 31, j = tid >> 5;
      float g_i = gL[b * 16 + (j << 2) + 0];
      float g_f = gL[b * 16 + (j << 2) + 1];
      float g_g = gL[b * 16 + (j << 2) + 2];
      float g_o = gL[b * 16 + (j << 2) + 3];
      c_reg = sigm(g_f) * c_reg + sigm(g_i) * tanhf(g_g);
      float h = sigm(g_o) * tanhf(c_reg);
      h_enc[(((cur ^ 1) * 2 + d) * 32 + b) * 512 + u0 + j] = h;
      if (s == 127) hcat[b * 1024 + d * 512 + u0 + j] = h;  // buf 0
    }
    gbar(flags, ++gen);
    cur ^= 1;
  }

  // ---------------- decoder: 63 steps ----------------
  for (int t = 0; t < 63; ++t) {
    const int p = t & 1;
    {  // stage [x | h_d] into xhL
      int b = tid >> 5, i = tid & 31;
      int tok;
      if (t == 0) {
        tok = tgt[b * 64];
      } else {
        unsigned long long kv = amax[(t - 1) * 32 + b];
        tok = (int)(0xFFFFFFFFu - (unsigned)(kv & 0xFFFFFFFFull));
      }
      const float* xr = dec_emb + (size_t)tok * 512;
      const float* hr = hcat + (size_t)p * 32768 + b * 1024 + d * 512;
#pragma unroll
      for (int q = 0; q < 4; ++q) {
        int k = (i + 32 * q) * 4;
        float4 v = *(const float4*)(xr + k);
        int pc = k + ((k >> 5) << 2);
        *(float4*)(xhL + b * XSTR + pc) = v;
      }
#pragma unroll
      for (int q = 0; q < 4; ++q) {
        int k = (i + 32 * q) * 4;
        float4 v = *(const float4*)(hr + k);
        int c2 = 512 + k;
        int pc = c2 + ((c2 >> 5) << 2);
        *(float4*)(xhL + b * XSTR + pc) = v;
      }
    }
    // reload decoder cell weights each step (frees VGPR for classifier)
    {
      const float* s0p = (ksD < 16) ? (dwih + (size_t)growD0 * 512 + ksD * 32)
                                    : (dwhh + (size_t)growD0 * 512 + (ksD - 16) * 32);
      const float* s1p = (ksD < 16) ? (dwih + (size_t)growD1 * 512 + ksD * 32)
                                    : (dwhh + (size_t)growD1 * 512 + (ksD - 16) * 32);
#pragma unroll
      for (int i4 = 0; i4 < 8; ++i4) {
        wA[i4] = *(const float4*)(s0p + i4 * 4);
        wB[i4] = *(const float4*)(s1p + i4 * 4);
      }
      biasA = dbih[growD0] + dbhh[growD0];
      biasB = dbih[growD1] + dbhh[growD1];
    }
    __syncthreads();
    for (int gi = 0; gi < 8; ++gi) {
      int b = bpD * 8 + gi;
      const float* hb = xhL + b * XSTR + ksD * 36;
      float4 a0 = {0, 0, 0, 0}, a1 = {0, 0, 0, 0};
#pragma unroll
      for (int i4 = 0; i4 < 8; ++i4) {
        float4 h4 = *(const float4*)(hb + i4 * 4);
        fma4(wA[i4], h4, a0);
        fma4(wB[i4], h4, a1);
      }
      float s0 = hsum4(a0), s1 = hsum4(a1);
#pragma unroll
      for (int m = 1; m <= 16; m <<= 1) {
        s0 += __shfl_xor(s0, m, 64);
        s1 += __shfl_xor(s1, m, 64);
      }
      if (ksD == 0) {
        gLd[b * 16 + r0D] = s0 + biasA;
        gLd[b * 16 + r1D] = s1 + biasB;
      }
    }
    __syncthreads();
    if (tid < 128) {
      int b = tid & 31, j = tid >> 5;
      float g_i = gLd[b * 16 + (j << 2) + 0];
      float g_f = gLd[b * 16 + (j << 2) + 1];
      float g_g = gLd[b * 16 + (j << 2) + 2];
      float g_o = gLd[b * 16 + (j << 2) + 3];
      c_reg = sigm(g_f) * c_reg + sigm(g_i) * tanhf(g_g);
      float h = sigm(g_o) * tanhf(c_reg);
      hcat[(size_t)(p ^ 1) * 32768 + b * 1024 + d * 512 + u0 + j] = h;
    }
    gbar(flags, ++gen);

    // ---- classifier v5: logits = h @ cls_w^T + cls_b, argmax ----
    // Spill-free under 64 VGPR: lane=(kc[0,4) k-chunk, bg[0,16) batch-pair),
    // wave owns rows wid*8..+7; acc[8][2]=16 regs; h b128 shared across rows.
    {  // stage h (plain row-major [32][1024]) into cH; zero amaxL
      const float* hr = hcat + (size_t)(p ^ 1) * 32768;
      float4* cH = (float4*)smem;
#pragma unroll
      for (int q = 0; q < 8; ++q) {
        int f = tid + q * 1024;
        cH[f] = *(const float4*)(hr + f * 4);
      }
      if (tid < 32) amaxL[tid] = 0ull;
    }
    __syncthreads();
    {
      const int wid = tid >> 6, lane = tid & 63;
      const int kc = lane & 3;          // k-chunk [0,4)
      const int bg = lane >> 2;         // batch pair [0,16)
      const int b0 = bg * 2, b1 = b0 + 1;
      const float4* cH = (const float4*)smem;

      // 8 row pointers (wave-uniform rows; +kc lane offset)
      const float4* wp[8];
#pragma unroll
      for (int r = 0; r < 8; ++r) {
        int lr = wid * 8 + r;
        lr = lr > 124 ? 124 : lr;
        wp[r] = (const float4*)cls_w + (((size_t)(bid * 125 + lr)) << 8) + kc;
      }

      float acc[16];
#pragma unroll
      for (int i = 0; i < 16; ++i) acc[i] = 0.f;

      const float4* hp0 = cH + b0 * 256 + kc;
      const float4* hp1 = cH + b1 * 256 + kc;
      for (int q = 0; q < 64; ++q) {
        const int k4 = q << 2;
        float4 h40 = hp0[k4];
        float4 h41 = hp1[k4];
        // rows 0..3
        {
          float4 w0 = wp[0][k4], w1 = wp[1][k4], w2 = wp[2][k4], w3 = wp[3][k4];
          acc[0] = dot4(w0, h40, acc[0]);  acc[1] = dot4(w0, h41, acc[1]);
          acc[2] = dot4(w1, h40, acc[2]);  acc[3] = dot4(w1, h41, acc[3]);
          acc[4] = dot4(w2, h40, acc[4]);  acc[5] = dot4(w2, h41, acc[5]);
          acc[6] = dot4(w3, h40, acc[6]);  acc[7] = dot4(w3, h41, acc[7]);
        }
        // rows 4..7
        {
          float4 w4 = wp[4][k4], w5 = wp[5][k4], w6 = wp[6][k4], w7 = wp[7][k4];
          acc[8]  = dot4(w4, h40, acc[8]);   acc[9]  = dot4(w4, h41, acc[9]);
          acc[10] = dot4(w5, h40, acc[10]);  acc[11] = dot4(w5, h41, acc[11]);
          acc[12] = dot4(w6, h40, acc[12]);  acc[13] = dot4(w6, h41, acc[13]);
          acc[14] = dot4(w7, h40, acc[14]);  acc[15] = dot4(w7, h41, acc[15]);
        }
      }

      // butterfly-sum over the 4 kc lanes (masks 1,2)
#pragma unroll
      for (int i = 0; i < 16; ++i) {
        acc[i] += __shfl_xor(acc[i], 1, 64);
        acc[i] += __shfl_xor(acc[i], 2, 64);
      }

      // static row-select tree: lane kc keeps rows rA=kc and rB=kc+4
      // acc index = r*2 + j
      float sA0, sA1, sB0, sB1;
      {
        float t0 = (kc & 1) ? acc[2]  : acc[0];
        float t1 = (kc & 1) ? acc[6]  : acc[4];
        sA0 = (kc & 2) ? t1 : t0;
        float u0v = (kc & 1) ? acc[3]  : acc[1];
        float u1v = (kc & 1) ? acc[7]  : acc[5];
        sA1 = (kc & 2) ? u1v : u0v;
        float v0v = (kc & 1) ? acc[10] : acc[8];
        float v1v = (kc & 1) ? acc[14] : acc[12];
        sB0 = (kc & 2) ? v1v : v0v;
        float w0v = (kc & 1) ? acc[11] : acc[9];
        float w1v = (kc & 1) ? acc[15] : acc[13];
        sB1 = (kc & 2) ? w1v : w0v;
      }

      const int lrA = wid * 8 + kc;        // <= 123, always valid
      const int lrB = lrA + 4;             // up to 127; >=125 invalid
      const int lrBc = lrB > 124 ? 124 : lrB;
      const int vrA = bid * 125 + lrA;
      const int vrB = bid * 125 + lrBc;
      const float cbA = cls_b[vrA];
      const float cbB = cls_b[vrB];
      const float lgA0 = sA0 + cbA, lgA1 = sA1 + cbA;
      const float lgB0 = sB0 + cbB, lgB1 = sB1 + cbB;

      // stage into oL[b][row_local] for coalesced writeback
      oL[b0 * 130 + lrA] = lgA0;
      oL[b1 * 130 + lrA] = lgA1;
      if (lrB < 125) {
        oL[b0 * 130 + lrB] = lgB0;
        oL[b1 * 130 + lrB] = lgB1;
      }

      // argmax keys; combine the 2 rows in-lane, then across kc lanes
      unsigned long long k0 = lgkey(lgA0, vrA);
      unsigned long long k1 = lgkey(lgA1, vrA);
      if (lrB < 125) {
        unsigned long long kB0 = lgkey(lgB0, vrB);
        unsigned long long kB1 = lgkey(lgB1, vrB);
        k0 = kB0 > k0 ? kB0 : k0;
        k1 = kB1 > k1 ? kB1 : k1;
      }
#pragma unroll
      for (int m = 1; m <= 2; m <<= 1) {
        unsigned long long o0 = __shfl_xor(k0, m, 64);
        unsigned long long o1 = __shfl_xor(k1, m, 64);
        k0 = o0 > k0 ? o0 : k0;
        k1 = o1 > k1 ? o1 : k1;
      }
      if (kc == 0) {
        atomicMax(&amaxL[b0], k0);
        atomicMax(&amaxL[b1], k1);
      }
    }
    __syncthreads();
    // coalesced logit writeback + global argmax merge
#pragma unroll
    for (int it = 0; it < 4; ++it) {
      int idx = tid + it * 1024;            // [0,4096)
      int b = idx >> 7, j = idx & 127;
      if (j < 125)
        out[((size_t)b * 64 + (t + 1)) * 32000 + bid * 125 + j] = oL[b * 130 + j];
    }
    if (tid < 32) atomicMax(&amax[t * 32 + tid], amaxL[tid]);
    gbar(flags, ++gen);
  }
}

extern "C" void kernel_launch(void* const* d_in, const int* in_sizes, int n_in,
                              void* d_out, int out_size, void* d_ws, size_t ws_size,
                              hipStream_t stream) {
  (void)in_sizes; (void)n_in; (void)out_size; (void)ws_size;
  const int*   src     = (const int*)d_in[0];
  const int*   tgt     = (const int*)d_in[1];
  const float* enc_emb = (const float*)d_in[2];
  const float* dec_emb = (const float*)d_in[3];
  const float* ewih_f  = (const float*)d_in[4];
  const float* ewhh_f  = (const float*)d_in[5];
  const float* ebih_f  = (const float*)d_in[6];
  const float* ebhh_f  = (const float*)d_in[7];
  const float* ewih_r  = (const float*)d_in[8];
  const float* ewhh_r  = (const float*)d_in[9];
  const float* ebih_r  = (const float*)d_in[10];
  const float* ebhh_r  = (const float*)d_in[11];
  const float* dwih_f  = (const float*)d_in[12];
  const float* dwhh_f  = (const float*)d_in[13];
  const float* dbih_f  = (const float*)d_in[14];
  const float* dbhh_f  = (const float*)d_in[15];
  const float* dwih_r  = (const float*)d_in[16];
  const float* dwhh_r  = (const float*)d_in[17];
  const float* dbih_r  = (const float*)d_in[18];
  const float* dbhh_r  = (const float*)d_in[19];
  const float* cls_w   = (const float*)d_in[20];
  const float* cls_b   = (const float*)d_in[21];

  char* ws = (char*)d_ws;
  unsigned long long* amax = (unsigned long long*)(ws + OFF_AMAX);
  unsigned* flags          = (unsigned*)(ws + OFF_FLAGS);
  float* Xg                = (float*)(ws + OFF_XG);
  float* h_enc             = (float*)(ws + OFF_HENC);
  float* hcat              = (float*)(ws + OFF_HCAT);

  // reset barrier flags + argmax slots (ws is poisoned 0xAA once before timing)
  hipMemsetAsync(d_ws, 0, OFF_XG, stream);

  static bool attr_set = []() {
    hipFuncSetAttribute((const void*)s2s_kernel,
                        hipFuncAttributeMaxDynamicSharedMemorySize, LDS_BYTES);
    return true;
  }();
  (void)attr_set;
  hipFuncSetAttribute((const void*)s2s_kernel,
                      hipFuncAttributeMaxDynamicSharedMemorySize, LDS_BYTES);

  hipLaunchKernelGGL(s2s_kernel, dim3(NBLK), dim3(NT), LDS_BYTES, stream,
                     src, tgt, enc_emb, dec_emb,
                     ewih_f, ewhh_f, ebih_f, ebhh_f,
                     ewih_r, ewhh_r, ebih_r, ebhh_r,
                     dwih_f, dwhh_f, dbih_f, dbhh_f,
                     dwih_r, dwhh_r, dbih_r, dbhh_r,
                     cls_w, cls_b,
                     (float*)d_out, amax, flags, Xg, h_enc, hcat);
}

// Round 6
// 16251.219 us; speedup vs baseline: 1.1768x; 1.1768x over previous
//
#include <hip/hip_runtime.h>
#include <stdint.h>

// Seq2Seq (bi-LSTM encoder + greedy LSTM decoder), MI355X gfx950.
// v6: three separable fixes.
//   R5 post-mortem: spill gone (WRITE 13.2->0.98 GB) but dur flat at ~19ms.
//   New evidence: LDS bank conflicts 5.6e8 (16-way on classifier h-reads),
//   hbm 472 GB/s (only ~4 w-loads in flight under 64-VGPR cap), and ~255
//   threadfence+256-flag grid barriers.
//   Fix 1: cH row stride 256->257 float4 => h-reads 2-way (free).
//   Fix 2: readfirstlane(wid) -> SGPR row bases; 8 w-loads/q in flight,
//          unroll 2 -> q-iterations overlap (classifier ~HBM-stream-bound).
//   Fix 3: counter+go-flag barrier (release add, 1-line acquire poll,
//          monotone generations) replaces threadfence + 256-flag poll.
//
// B=32 S=128 T=64 V=32000 E=512 H=512 (4H=2048 gates per cell)

#define NT 1024
#define NBLK 256

constexpr int HSTR = 580;    // enc h-stage LDS row stride (512 + pad, %32==4)
constexpr int XSTR = 1156;   // dec [x|h]-stage stride (1024 + pad, %32==4)
constexpr unsigned LDS_BYTES = 150528;

// workspace layout (bytes)
constexpr size_t OFF_AMAX  = 0;                     // 63*32 u64 = 16128
constexpr size_t OFF_FLAGS = 16128;                 // cnt @ +0, go @ +256
constexpr size_t OFF_XG    = 17408;                 // 256*128*32*16 f32 = 67108864
constexpr size_t OFF_HENC  = OFF_XG + 67108864ULL;  // 2buf*2dir*32*512 f32 = 262144
constexpr size_t OFF_HCAT  = OFF_HENC + 262144ULL;  // 2buf*32*1024 f32 = 262144

__device__ __forceinline__ float sigm(float x) {
  if (x >= 0.f) return 1.f / (1.f + expf(-x));
  float e = expf(x);
  return e / (1.f + e);
}

__device__ __forceinline__ void fma4(const float4& w, const float4& h, float4& a) {
  a.x = fmaf(w.x, h.x, a.x);
  a.y = fmaf(w.y, h.y, a.y);
  a.z = fmaf(w.z, h.z, a.z);
  a.w = fmaf(w.w, h.w, a.w);
}

__device__ __forceinline__ float hsum4(const float4& a) {
  return (a.x + a.y) + (a.z + a.w);
}

__device__ __forceinline__ float dot4(const float4& w, const float4& h, float acc) {
  return fmaf(w.x, h.x, fmaf(w.y, h.y, fmaf(w.z, h.z, fmaf(w.w, h.w, acc))));
}

__device__ __forceinline__ unsigned long long lgkey(float lg, int vr) {
  unsigned u = __float_as_uint(lg);
  u = (u & 0x80000000u) ? ~u : (u | 0x80000000u);
  return ((unsigned long long)u << 32) | (0xFFFFFFFFu - (unsigned)vr);
}

// device-scope counter barrier: release fetch_add; last arriver publishes go;
// everyone acquire-polls the single go word. Generations are monotone, no reset.
__device__ __forceinline__ void gbar(unsigned* cnt, unsigned* go, unsigned gen) {
  __syncthreads();
  if (threadIdx.x == 0) {
    unsigned old = __hip_atomic_fetch_add(cnt, 1u, __ATOMIC_ACQ_REL,
                                          __HIP_MEMORY_SCOPE_AGENT);
    if (old == gen * NBLK - 1u) {
      __hip_atomic_store(go, gen, __ATOMIC_RELEASE, __HIP_MEMORY_SCOPE_AGENT);
    } else {
      while (__hip_atomic_load(go, __ATOMIC_ACQUIRE,
                               __HIP_MEMORY_SCOPE_AGENT) < gen) {
        __builtin_amdgcn_s_sleep(1);
      }
    }
  }
  __syncthreads();
}

__global__ __launch_bounds__(NT, 4) void s2s_kernel(
    const int* __restrict__ src, const int* __restrict__ tgt,
    const float* __restrict__ enc_emb, const float* __restrict__ dec_emb,
    const float* __restrict__ ewih_f, const float* __restrict__ ewhh_f,
    const float* __restrict__ ebih_f, const float* __restrict__ ebhh_f,
    const float* __restrict__ ewih_r, const float* __restrict__ ewhh_r,
    const float* __restrict__ ebih_r, const float* __restrict__ ebhh_r,
    const float* __restrict__ dwih_f, const float* __restrict__ dwhh_f,
    const float* __restrict__ dbih_f, const float* __restrict__ dbhh_f,
    const float* __restrict__ dwih_r, const float* __restrict__ dwhh_r,
    const float* __restrict__ dbih_r, const float* __restrict__ dbhh_r,
    const float* __restrict__ cls_w, const float* __restrict__ cls_b,
    float* __restrict__ out,
    unsigned long long* __restrict__ amax, unsigned* __restrict__ flags,
    float* __restrict__ Xg, float* __restrict__ h_enc, float* __restrict__ hcat) {
  extern __shared__ float smem[];
  const int tid = threadIdx.x;
  const int bid = blockIdx.x;
  const int d  = bid >> 7;          // 0 = forward, 1 = reverse
  const int u0 = (bid & 127) << 2;  // first of 4 owned LSTM units

  unsigned* g_cnt = flags;          // single counter
  unsigned* g_go  = flags + 64;     // go word on its own 256B line

  // LDS views per phase (aliased)
  float* hL  = smem;                      // enc: [32][HSTR]
  float* XgL = smem + 32 * HSTR;          // enc: [32*16]
  float* gL  = XgL + 512;                 // enc: [32*16]
  float* xhL = smem;                      // dec cell: [32][XSTR]
  float* gLd = smem + 32 * XSTR;          // dec cell: [32*16]
  // classifier phase: cH float4[32][257] at floats [0, 32896)
  //                   oL [32][130] at floats [32896, 37056)
  //                   amaxL u64[32] at floats [37504, 37568)
  float* oL = smem + 32896;
  unsigned long long* amaxL = (unsigned long long*)(smem + 37504);

  // mapping E (phase0 + encoder scan): 2 rows x 4 b per thread, k-split 16
  const int rgE = tid >> 7;               // [0,8)
  const int bpE = (tid >> 4) & 7;         // [0,8)
  const int ksE = tid & 15;               // [0,16)
  const int r0E = rgE * 2, r1E = r0E + 1;
  const int growE0 = (r0E & 3) * 512 + u0 + (r0E >> 2);
  const int growE1 = (r1E & 3) * 512 + u0 + (r1E >> 2);
  // mapping D (decoder cells): 2 rows x 8 b per thread, k-split 32 over K=1024
  const int rgD = tid >> 7;
  const int bpD = (tid >> 5) & 3;         // [0,4)
  const int ksD = tid & 31;               // [0,32)
  const int r0D = rgD * 2, r1D = r0D + 1;
  const int growD0 = (r0D & 3) * 512 + u0 + (r0D >> 2);
  const int growD1 = (r1D & 3) * 512 + u0 + (r1D >> 2);

  const float* ewih = d ? ewih_r : ewih_f;
  const float* ewhh = d ? ewhh_r : ewhh_f;
  const float* ebih = d ? ebih_r : ebih_f;
  const float* ebhh = d ? ebhh_r : ebhh_f;
  const float* dwih = d ? dwih_r : dwih_f;
  const float* dwhh = d ? dwhh_r : dwhh_f;
  const float* dbih = d ? dbih_r : dbih_f;
  const float* dbhh = d ? dbhh_r : dbhh_f;

  float4 wA[8], wB[8];
  float biasA, biasB;
  float c_reg = 0.f;   // cell state for threads tid<128 (b=tid&31, j=tid>>5)
  unsigned gen = 0;

  // ---------------- phase 0: Xg = emb(src) @ wih^T + bih + bhh ----------------
#pragma unroll
  for (int i4 = 0; i4 < 8; ++i4) {
    wA[i4] = *(const float4*)(ewih + (size_t)growE0 * 512 + ksE * 32 + i4 * 4);
    wB[i4] = *(const float4*)(ewih + (size_t)growE1 * 512 + ksE * 32 + i4 * 4);
  }
  biasA = ebih[growE0] + ebhh[growE0];
  biasB = ebih[growE1] + ebhh[growE1];

  for (int t = 0; t < 128; ++t) {
    {  // stage x = enc_emb[src[b][t]] into hL
      int b = tid >> 5, i = tid & 31;
      int tok = src[b * 128 + t];
      const float* row = enc_emb + (size_t)tok * 512;
#pragma unroll
      for (int q = 0; q < 4; ++q) {
        int k = (i + 32 * q) * 4;
        float4 v = *(const float4*)(row + k);
        int pc = k + ((k >> 5) << 2);
        *(float4*)(hL + b * HSTR + pc) = v;
      }
    }
    __syncthreads();
    for (int gi = 0; gi < 4; ++gi) {
      int b = bpE * 4 + gi;
      const float* hb = hL + b * HSTR + ksE * 36;
      float4 a0 = {0, 0, 0, 0}, a1 = {0, 0, 0, 0};
#pragma unroll
      for (int i4 = 0; i4 < 8; ++i4) {
        float4 h4 = *(const float4*)(hb + i4 * 4);
        fma4(wA[i4], h4, a0);
        fma4(wB[i4], h4, a1);
      }
      float s0 = hsum4(a0), s1 = hsum4(a1);
#pragma unroll
      for (int m = 1; m <= 8; m <<= 1) {
        s0 += __shfl_xor(s0, m, 64);
        s1 += __shfl_xor(s1, m, 64);
      }
      if (ksE == 0) {
        float* xgp = Xg + ((size_t)bid << 16) + t * 512 + b * 16;
        xgp[r0E] = s0 + biasA;
        xgp[r1E] = s1 + biasB;
      }
    }
    __syncthreads();
  }

  // init h_enc[buf0] = 0 for owned units; zero out[:,0,:] slice
  if (tid < 128) {
    int b = tid & 31, j = tid >> 5;
    h_enc[((0 * 2 + d) * 32 + b) * 512 + u0 + j] = 0.f;
  }
  for (int i = tid; i < 4000; i += NT) {
    int b = i & 31, vv = i >> 5;  // vv < 125
    out[(size_t)b * 64 * 32000 + bid * 125 + vv] = 0.f;
  }
  gbar(g_cnt, g_go, ++gen);

  // ---------------- encoder scan: 128 steps ----------------
#pragma unroll
  for (int i4 = 0; i4 < 8; ++i4) {
    wA[i4] = *(const float4*)(ewhh + (size_t)growE0 * 512 + ksE * 32 + i4 * 4);
    wB[i4] = *(const float4*)(ewhh + (size_t)growE1 * 512 + ksE * 32 + i4 * 4);
  }
  int cur = 0;
  for (int s = 0; s < 128; ++s) {
    const int td = d ? (127 - s) : s;
    {  // stage h_enc[cur][d] -> hL; stage this block's Xg slice -> XgL
      int b = tid >> 5, i = tid & 31;
      const float* hr = h_enc + ((size_t)(cur * 2 + d) * 32 + b) * 512;
#pragma unroll
      for (int q = 0; q < 4; ++q) {
        int k = (i + 32 * q) * 4;
        float4 v = *(const float4*)(hr + k);
        int pc = k + ((k >> 5) << 2);
        *(float4*)(hL + b * HSTR + pc) = v;
      }
      if (tid < 128) {
        ((float4*)XgL)[tid] =
            *(const float4*)(Xg + ((size_t)bid << 16) + td * 512 + tid * 4);
      }
    }
    __syncthreads();
    for (int gi = 0; gi < 4; ++gi) {
      int b = bpE * 4 + gi;
      const float* hb = hL + b * HSTR + ksE * 36;
      float4 a0 = {0, 0, 0, 0}, a1 = {0, 0, 0, 0};
#pragma unroll
      for (int i4 = 0; i4 < 8; ++i4) {
        float4 h4 = *(const float4*)(hb + i4 * 4);
        fma4(wA[i4], h4, a0);
        fma4(wB[i4], h4, a1);
      }
      float s0 = hsum4(a0), s1 = hsum4(a1);
#pragma unroll
      for (int m = 1; m <= 8; m <<= 1) {
        s0 += __shfl_xor(s0, m, 64);
        s1 += __shfl_xor(s1, m, 64);
      }
      if (ksE == 0) {
        gL[b * 16 + r0E] = s0 + XgL[b * 16 + r0E];
        gL[b * 16 + r1E] = s1 + XgL[b * 16 + r1E];
      }
    }
    __syncthreads();
    if (tid < 128) {
      int b = tid & 31, j = tid >> 5;
      float g_i = gL[b * 16 + (j << 2) + 0];
      float g_f = gL[b * 16 + (j << 2) + 1];
      float g_g = gL[b * 16 + (j << 2) + 2];
      float g_o = gL[b * 16 + (j << 2) + 3];
      c_reg = sigm(g_f) * c_reg + sigm(g_i) * tanhf(g_g);
      float h = sigm(g_o) * tanhf(c_reg);
      h_enc[(((cur ^ 1) * 2 + d) * 32 + b) * 512 + u0 + j] = h;
      if (s == 127) hcat[b * 1024 + d * 512 + u0 + j] = h;  // buf 0
    }
    gbar(g_cnt, g_go, ++gen);
    cur ^= 1;
  }

  // ---------------- decoder: 63 steps ----------------
  for (int t = 0; t < 63; ++t) {
    const int p = t & 1;
    {  // stage [x | h_d] into xhL
      int b = tid >> 5, i = tid & 31;
      int tok;
      if (t == 0) {
        tok = tgt[b * 64];
      } else {
        unsigned long long kv = amax[(t - 1) * 32 + b];
        tok = (int)(0xFFFFFFFFu - (unsigned)(kv & 0xFFFFFFFFull));
      }
      const float* xr = dec_emb + (size_t)tok * 512;
      const float* hr = hcat + (size_t)p * 32768 + b * 1024 + d * 512;
#pragma unroll
      for (int q = 0; q < 4; ++q) {
        int k = (i + 32 * q) * 4;
        float4 v = *(const float4*)(xr + k);
        int pc = k + ((k >> 5) << 2);
        *(float4*)(xhL + b * XSTR + pc) = v;
      }
#pragma unroll
      for (int q = 0; q < 4; ++q) {
        int k = (i + 32 * q) * 4;
        float4 v = *(const float4*)(hr + k);
        int c2 = 512 + k;
        int pc = c2 + ((c2 >> 5) << 2);
        *(float4*)(xhL + b * XSTR + pc) = v;
      }
    }
    // reload decoder cell weights each step (frees VGPR for classifier)
    {
      const float* s0p = (ksD < 16) ? (dwih + (size_t)growD0 * 512 + ksD * 32)
                                    : (dwhh + (size_t)growD0 * 512 + (ksD - 16) * 32);
      const float* s1p = (ksD < 16) ? (dwih + (size_t)growD1 * 512 + ksD * 32)
                                    : (dwhh + (size_t)growD1 * 512 + (ksD - 16) * 32);
#pragma unroll
      for (int i4 = 0; i4 < 8; ++i4) {
        wA[i4] = *(const float4*)(s0p + i4 * 4);
        wB[i4] = *(const float4*)(s1p + i4 * 4);
      }
      biasA = dbih[growD0] + dbhh[growD0];
      biasB = dbih[growD1] + dbhh[growD1];
    }
    __syncthreads();
    for (int gi = 0; gi < 8; ++gi) {
      int b = bpD * 8 + gi;
      const float* hb = xhL + b * XSTR + ksD * 36;
      float4 a0 = {0, 0, 0, 0}, a1 = {0, 0, 0, 0};
#pragma unroll
      for (int i4 = 0; i4 < 8; ++i4) {
        float4 h4 = *(const float4*)(hb + i4 * 4);
        fma4(wA[i4], h4, a0);
        fma4(wB[i4], h4, a1);
      }
      float s0 = hsum4(a0), s1 = hsum4(a1);
#pragma unroll
      for (int m = 1; m <= 16; m <<= 1) {
        s0 += __shfl_xor(s0, m, 64);
        s1 += __shfl_xor(s1, m, 64);
      }
      if (ksD == 0) {
        gLd[b * 16 + r0D] = s0 + biasA;
        gLd[b * 16 + r1D] = s1 + biasB;
      }
    }
    __syncthreads();
    if (tid < 128) {
      int b = tid & 31, j = tid >> 5;
      float g_i = gLd[b * 16 + (j << 2) + 0];
      float g_f = gLd[b * 16 + (j << 2) + 1];
      float g_g = gLd[b * 16 + (j << 2) + 2];
      float g_o = gLd[b * 16 + (j << 2) + 3];
      c_reg = sigm(g_f) * c_reg + sigm(g_i) * tanhf(g_g);
      float h = sigm(g_o) * tanhf(c_reg);
      hcat[(size_t)(p ^ 1) * 32768 + b * 1024 + d * 512 + u0 + j] = h;
    }
    gbar(g_cnt, g_go, ++gen);

    // ---- classifier v6: logits = h @ cls_w^T + cls_b, argmax ----
    // lane=(kc[0,4), bg[0,16)); wave owns rows widu*8..+7 (SGPR bases via
    // readfirstlane); cH padded [32][257] float4 -> 2-way LDS (free).
    {  // stage h transpose-free into padded cH; zero amaxL
      const float4* hr4 = (const float4*)(hcat + (size_t)(p ^ 1) * 32768);
      float4* cH4w = (float4*)smem;
#pragma unroll
      for (int q = 0; q < 8; ++q) {
        int f = tid + q * 1024;
        int b = f >> 8, k4 = f & 255;
        cH4w[b * 257 + k4] = hr4[f];
      }
      if (tid < 32) amaxL[tid] = 0ull;
    }
    __syncthreads();
    {
      const int lane = tid & 63;
      const int widu = __builtin_amdgcn_readfirstlane(tid >> 6);  // wave-uniform
      const int kc = lane & 3;          // k-chunk [0,4)
      const int bg = lane >> 2;         // batch pair [0,16)
      const int b0 = bg * 2, b1 = b0 + 1;
      const float4* cH4 = (const float4*)smem;

      // 8 wave-uniform row bases -> SGPRs (frees VGPRs for load pipelining)
      const float* wr[8];
#pragma unroll
      for (int r = 0; r < 8; ++r) {
        int lr = widu * 8 + r;
        lr = lr > 124 ? 124 : lr;
        wr[r] = cls_w + (size_t)(bid * 125 + lr) * 1024;
      }

      float acc[16];
#pragma unroll
      for (int i = 0; i < 16; ++i) acc[i] = 0.f;

      const float4* hp0 = cH4 + b0 * 257 + kc;
      const float4* hp1 = cH4 + b1 * 257 + kc;
      const int fo = kc * 4;  // per-lane float offset within a 16-float k-group
#pragma unroll 2
      for (int q = 0; q < 64; ++q) {
        const int ko = q * 16 + fo;
        float4 w0 = *(const float4*)(wr[0] + ko);
        float4 w1 = *(const float4*)(wr[1] + ko);
        float4 w2 = *(const float4*)(wr[2] + ko);
        float4 w3 = *(const float4*)(wr[3] + ko);
        float4 w4 = *(const float4*)(wr[4] + ko);
        float4 w5 = *(const float4*)(wr[5] + ko);
        float4 w6 = *(const float4*)(wr[6] + ko);
        float4 w7 = *(const float4*)(wr[7] + ko);
        float4 h40 = hp0[q * 4];
        float4 h41 = hp1[q * 4];
        acc[0]  = dot4(w0, h40, acc[0]);   acc[1]  = dot4(w0, h41, acc[1]);
        acc[2]  = dot4(w1, h40, acc[2]);   acc[3]  = dot4(w1, h41, acc[3]);
        acc[4]  = dot4(w2, h40, acc[4]);   acc[5]  = dot4(w2, h41, acc[5]);
        acc[6]  = dot4(w3, h40, acc[6]);   acc[7]  = dot4(w3, h41, acc[7]);
        acc[8]  = dot4(w4, h40, acc[8]);   acc[9]  = dot4(w4, h41, acc[9]);
        acc[10] = dot4(w5, h40, acc[10]);  acc[11] = dot4(w5, h41, acc[11]);
        acc[12] = dot4(w6, h40, acc[12]);  acc[13] = dot4(w6, h41, acc[13]);
        acc[14] = dot4(w7, h40, acc[14]);  acc[15] = dot4(w7, h41, acc[15]);
      }

      // butterfly-sum over the 4 kc lanes (masks 1,2)
#pragma unroll
      for (int i = 0; i < 16; ++i) {
        acc[i] += __shfl_xor(acc[i], 1, 64);
        acc[i] += __shfl_xor(acc[i], 2, 64);
      }

      // static row-select tree: lane kc keeps rows rA=kc and rB=kc+4
      float sA0, sA1, sB0, sB1;
      {
        float t0 = (kc & 1) ? acc[2]  : acc[0];
        float t1 = (kc & 1) ? acc[6]  : acc[4];
        sA0 = (kc & 2) ? t1 : t0;
        float u0v = (kc & 1) ? acc[3]  : acc[1];
        float u1v = (kc & 1) ? acc[7]  : acc[5];
        sA1 = (kc & 2) ? u1v : u0v;
        float v0v = (kc & 1) ? acc[10] : acc[8];
        float v1v = (kc & 1) ? acc[14] : acc[12];
        sB0 = (kc & 2) ? v1v : v0v;
        float w0v = (kc & 1) ? acc[11] : acc[9];
        float w1v = (kc & 1) ? acc[15] : acc[13];
        sB1 = (kc & 2) ? w1v : w0v;
      }

      const int lrA = widu * 8 + kc;       // <= 123, always valid
      const int lrB = lrA + 4;             // up to 127; >=125 invalid
      const int lrBc = lrB > 124 ? 124 : lrB;
      const int vrA = bid * 125 + lrA;
      const int vrB = bid * 125 + lrBc;
      const float cbA = cls_b[vrA];
      const float cbB = cls_b[vrB];
      const float lgA0 = sA0 + cbA, lgA1 = sA1 + cbA;
      const float lgB0 = sB0 + cbB, lgB1 = sB1 + cbB;

      // stage into oL[b][row_local] for coalesced writeback
      oL[b0 * 130 + lrA] = lgA0;
      oL[b1 * 130 + lrA] = lgA1;
      if (lrB < 125) {
        oL[b0 * 130 + lrB] = lgB0;
        oL[b1 * 130 + lrB] = lgB1;
      }

      // argmax keys; combine the 2 rows in-lane, then across kc lanes
      unsigned long long k0 = lgkey(lgA0, vrA);
      unsigned long long k1 = lgkey(lgA1, vrA);
      if (lrB < 125) {
        unsigned long long kB0 = lgkey(lgB0, vrB);
        unsigned long long kB1 = lgkey(lgB1, vrB);
        k0 = kB0 > k0 ? kB0 : k0;
        k1 = kB1 > k1 ? kB1 : k1;
      }
#pragma unroll
      for (int m = 1; m <= 2; m <<= 1) {
        unsigned long long o0 = __shfl_xor(k0, m, 64);
        unsigned long long o1 = __shfl_xor(k1, m, 64);
        k0 = o0 > k0 ? o0 : k0;
        k1 = o1 > k1 ? o1 : k1;
      }
      if (kc == 0) {
        atomicMax(&amaxL[b0], k0);
        atomicMax(&amaxL[b1], k1);
      }
    }
    __syncthreads();
    // coalesced logit writeback + global argmax merge
#pragma unroll
    for (int it = 0; it < 4; ++it) {
      int idx = tid + it * 1024;            // [0,4096)
      int b = idx >> 7, j = idx & 127;
      if (j < 125)
        out[((size_t)b * 64 + (t + 1)) * 32000 + bid * 125 + j] = oL[b * 130 + j];
    }
    if (tid < 32) atomicMax(&amax[t * 32 + tid], amaxL[tid]);
    gbar(g_cnt, g_go, ++gen);
  }
}

extern "C" void kernel_launch(void* const* d_in, const int* in_sizes, int n_in,
                              void* d_out, int out_size, void* d_ws, size_t ws_size,
                              hipStream_t stream) {
  (void)in_sizes; (void)n_in; (void)out_size; (void)ws_size;
  const int*   src     = (const int*)d_in[0];
  const int*   tgt     = (const int*)d_in[1];
  const float* enc_emb = (const float*)d_in[2];
  const float* dec_emb = (const float*)d_in[3];
  const float* ewih_f  = (const float*)d_in[4];
  const float* ewhh_f  = (const float*)d_in[5];
  const float* ebih_f  = (const float*)d_in[6];
  const float* ebhh_f  = (const float*)d_in[7];
  const float* ewih_r  = (const float*)d_in[8];
  const float* ewhh_r  = (const float*)d_in[9];
  const float* ebih_r  = (const float*)d_in[10];
  const float* ebhh_r  = (const float*)d_in[11];
  const float* dwih_f  = (const float*)d_in[12];
  const float* dwhh_f  = (const float*)d_in[13];
  const float* dbih_f  = (const float*)d_in[14];
  const float* dbhh_f  = (const float*)d_in[15];
  const float* dwih_r  = (const float*)d_in[16];
  const float* dwhh_r  = (const float*)d_in[17];
  const float* dbih_r  = (const float*)d_in[18];
  const float* dbhh_r  = (const float*)d_in[19];
  const float* cls_w   = (const float*)d_in[20];
  const float* cls_b   = (const float*)d_in[21];

  char* ws = (char*)d_ws;
  unsigned long long* amax = (unsigned long long*)(ws + OFF_AMAX);
  unsigned* flags          = (unsigned*)(ws + OFF_FLAGS);
  float* Xg                = (float*)(ws + OFF_XG);
  float* h_enc             = (float*)(ws + OFF_HENC);
  float* hcat              = (float*)(ws + OFF_HCAT);

  // reset barrier counter/go + argmax slots (ws is poisoned 0xAA once)
  hipMemsetAsync(d_ws, 0, OFF_XG, stream);

  static bool attr_set = []() {
    hipFuncSetAttribute((const void*)s2s_kernel,
                        hipFuncAttributeMaxDynamicSharedMemorySize, LDS_BYTES);
    return true;
  }();
  (void)attr_set;
  hipFuncSetAttribute((const void*)s2s_kernel,
                      hipFuncAttributeMaxDynamicSharedMemorySize, LDS_BYTES);

  hipLaunchKernelGGL(s2s_kernel, dim3(NBLK), dim3(NT), LDS_BYTES, stream,
                     src, tgt, enc_emb, dec_emb,
                     ewih_f, ewhh_f, ebih_f, ebhh_f,
                     ewih_r, ewhh_r, ebih_r, ebhh_r,
                     dwih_f, dwhh_f, dbih_f, dbhh_f,
                     dwih_r, dwhh_r, dbih_r, dbhh_r,
                     cls_w, cls_b,
                     (float*)d_out, amax, flags, Xg, h_enc, hcat);
}

// Round 7
// 7608.294 us; speedup vs baseline: 2.5137x; 2.1360x over previous
//
#include <hip/hip_runtime.h>
#include <stdint.h>

// Seq2Seq (bi-LSTM encoder + greedy LSTM decoder), MI355X gfx950.
// v7: persistent kernel + grid barriers -> 255-node kernel sequence.
//   R6 post-mortem: phase rooflines sum to ~3ms but dur=16.25ms; aggregate
//   counters can't attribute. Prime suspect: ~255 device-scope grid barriers
//   (256 contended RMWs ping-ponging across 8 non-coherent XCD L2s, ~40-60us
//   each). Fix + instrumentation in one: each dependency step becomes its own
//   kernel launch (graph-captured chain). c-state moves to ws (131KB/step).
//   Classifier kept byte-identical to v6 to isolate the variable; rocprof now
//   times each phase separately.
//
// B=32 S=128 T=64 V=32000 E=512 H=512 (4H=2048 gates per cell)

#define NT 1024
#define NBLK 256

constexpr int HSTR = 580;    // enc h-stage LDS row stride (512 + pad, %32==4)
constexpr int XSTR = 1156;   // dec [x|h]-stage stride (1024 + pad, %32==4)
constexpr unsigned LDS_ENC = 78336;    // (32*580 + 512 + 512) floats
constexpr unsigned LDS_CELL = 150016;  // (32*1156 + 512) floats
constexpr unsigned LDS_CLS = 150528;   // cH + oL + amaxL

// workspace layout (bytes)
constexpr size_t OFF_AMAX  = 0;                     // 63*32 u64 = 16128
constexpr size_t OFF_FLAGS = 16128;                 // unused (kept for memset span)
constexpr size_t OFF_XG    = 17408;                 // 256*128*32*16 f32 = 67108864
constexpr size_t OFF_HENC  = OFF_XG + 67108864ULL;  // 2buf*2dir*32*512 f32 = 262144
constexpr size_t OFF_HCAT  = OFF_HENC + 262144ULL;  // 2buf*32*1024 f32 = 262144
constexpr size_t OFF_CST   = OFF_HCAT + 262144ULL;  // 2dir*32*512 f32 = 131072

__device__ __forceinline__ float sigm(float x) {
  if (x >= 0.f) return 1.f / (1.f + expf(-x));
  float e = expf(x);
  return e / (1.f + e);
}

__device__ __forceinline__ void fma4(const float4& w, const float4& h, float4& a) {
  a.x = fmaf(w.x, h.x, a.x);
  a.y = fmaf(w.y, h.y, a.y);
  a.z = fmaf(w.z, h.z, a.z);
  a.w = fmaf(w.w, h.w, a.w);
}

__device__ __forceinline__ float hsum4(const float4& a) {
  return (a.x + a.y) + (a.z + a.w);
}

__device__ __forceinline__ float dot4(const float4& w, const float4& h, float acc) {
  return fmaf(w.x, h.x, fmaf(w.y, h.y, fmaf(w.z, h.z, fmaf(w.w, h.w, acc))));
}

__device__ __forceinline__ unsigned long long lgkey(float lg, int vr) {
  unsigned u = __float_as_uint(lg);
  u = (u & 0x80000000u) ? ~u : (u | 0x80000000u);
  return ((unsigned long long)u << 32) | (0xFFFFFFFFu - (unsigned)vr);
}

// ---------------- K0: Xg = emb(src) @ wih^T + bih + bhh; init h_enc, out ----
__global__ __launch_bounds__(NT) void k_xg(
    const int* __restrict__ src, const float* __restrict__ enc_emb,
    const float* __restrict__ ewih_f, const float* __restrict__ ebih_f,
    const float* __restrict__ ebhh_f,
    const float* __restrict__ ewih_r, const float* __restrict__ ebih_r,
    const float* __restrict__ ebhh_r,
    float* __restrict__ Xg, float* __restrict__ h_enc, float* __restrict__ out) {
  extern __shared__ float smem[];
  const int tid = threadIdx.x;
  const int bid = blockIdx.x;
  const int d  = bid >> 7;
  const int u0 = (bid & 127) << 2;

  float* hL  = smem;               // [32][HSTR]

  const int rgE = tid >> 7;
  const int bpE = (tid >> 4) & 7;
  const int ksE = tid & 15;
  const int r0E = rgE * 2, r1E = r0E + 1;
  const int growE0 = (r0E & 3) * 512 + u0 + (r0E >> 2);
  const int growE1 = (r1E & 3) * 512 + u0 + (r1E >> 2);

  const float* ewih = d ? ewih_r : ewih_f;
  const float* ebih = d ? ebih_r : ebih_f;
  const float* ebhh = d ? ebhh_r : ebhh_f;

  float4 wA[8], wB[8];
#pragma unroll
  for (int i4 = 0; i4 < 8; ++i4) {
    wA[i4] = *(const float4*)(ewih + (size_t)growE0 * 512 + ksE * 32 + i4 * 4);
    wB[i4] = *(const float4*)(ewih + (size_t)growE1 * 512 + ksE * 32 + i4 * 4);
  }
  const float biasA = ebih[growE0] + ebhh[growE0];
  const float biasB = ebih[growE1] + ebhh[growE1];

  for (int t = 0; t < 128; ++t) {
    {
      int b = tid >> 5, i = tid & 31;
      int tok = src[b * 128 + t];
      const float* row = enc_emb + (size_t)tok * 512;
#pragma unroll
      for (int q = 0; q < 4; ++q) {
        int k = (i + 32 * q) * 4;
        float4 v = *(const float4*)(row + k);
        int pc = k + ((k >> 5) << 2);
        *(float4*)(hL + b * HSTR + pc) = v;
      }
    }
    __syncthreads();
    for (int gi = 0; gi < 4; ++gi) {
      int b = bpE * 4 + gi;
      const float* hb = hL + b * HSTR + ksE * 36;
      float4 a0 = {0, 0, 0, 0}, a1 = {0, 0, 0, 0};
#pragma unroll
      for (int i4 = 0; i4 < 8; ++i4) {
        float4 h4 = *(const float4*)(hb + i4 * 4);
        fma4(wA[i4], h4, a0);
        fma4(wB[i4], h4, a1);
      }
      float s0 = hsum4(a0), s1 = hsum4(a1);
#pragma unroll
      for (int m = 1; m <= 8; m <<= 1) {
        s0 += __shfl_xor(s0, m, 64);
        s1 += __shfl_xor(s1, m, 64);
      }
      if (ksE == 0) {
        float* xgp = Xg + ((size_t)bid << 16) + t * 512 + b * 16;
        xgp[r0E] = s0 + biasA;
        xgp[r1E] = s1 + biasB;
      }
    }
    __syncthreads();
  }

  if (tid < 128) {
    int b = tid & 31, j = tid >> 5;
    h_enc[((0 * 2 + d) * 32 + b) * 512 + u0 + j] = 0.f;
  }
  for (int i = tid; i < 4000; i += NT) {
    int b = i & 31, vv = i >> 5;  // vv < 125
    out[(size_t)b * 64 * 32000 + bid * 125 + vv] = 0.f;
  }
}

// ---------------- K_enc: one bi-LSTM encoder time step ----------------
__global__ __launch_bounds__(NT) void k_enc(
    const float* __restrict__ ewhh_f, const float* __restrict__ ewhh_r,
    const float* __restrict__ Xg, float* __restrict__ h_enc,
    float* __restrict__ hcat, float* __restrict__ c_st, int s) {
  extern __shared__ float smem[];
  const int tid = threadIdx.x;
  const int bid = blockIdx.x;
  const int d  = bid >> 7;
  const int u0 = (bid & 127) << 2;
  const int cur = s & 1;
  const int td = d ? (127 - s) : s;

  float* hL  = smem;               // [32][HSTR]
  float* XgL = smem + 32 * HSTR;   // [32*16]
  float* gL  = XgL + 512;          // [32*16]

  const int rgE = tid >> 7;
  const int bpE = (tid >> 4) & 7;
  const int ksE = tid & 15;
  const int r0E = rgE * 2, r1E = r0E + 1;
  const int growE0 = (r0E & 3) * 512 + u0 + (r0E >> 2);
  const int growE1 = (r1E & 3) * 512 + u0 + (r1E >> 2);

  const float* ewhh = d ? ewhh_r : ewhh_f;

  float4 wA[8], wB[8];
#pragma unroll
  for (int i4 = 0; i4 < 8; ++i4) {
    wA[i4] = *(const float4*)(ewhh + (size_t)growE0 * 512 + ksE * 32 + i4 * 4);
    wB[i4] = *(const float4*)(ewhh + (size_t)growE1 * 512 + ksE * 32 + i4 * 4);
  }

  {
    int b = tid >> 5, i = tid & 31;
    const float* hr = h_enc + ((size_t)(cur * 2 + d) * 32 + b) * 512;
#pragma unroll
    for (int q = 0; q < 4; ++q) {
      int k = (i + 32 * q) * 4;
      float4 v = *(const float4*)(hr + k);
      int pc = k + ((k >> 5) << 2);
      *(float4*)(hL + b * HSTR + pc) = v;
    }
    if (tid < 128) {
      ((float4*)XgL)[tid] =
          *(const float4*)(Xg + ((size_t)bid << 16) + td * 512 + tid * 4);
    }
  }
  __syncthreads();
  for (int gi = 0; gi < 4; ++gi) {
    int b = bpE * 4 + gi;
    const float* hb = hL + b * HSTR + ksE * 36;
    float4 a0 = {0, 0, 0, 0}, a1 = {0, 0, 0, 0};
#pragma unroll
    for (int i4 = 0; i4 < 8; ++i4) {
      float4 h4 = *(const float4*)(hb + i4 * 4);
      fma4(wA[i4], h4, a0);
      fma4(wB[i4], h4, a1);
    }
    float s0 = hsum4(a0), s1 = hsum4(a1);
#pragma unroll
    for (int m = 1; m <= 8; m <<= 1) {
      s0 += __shfl_xor(s0, m, 64);
      s1 += __shfl_xor(s1, m, 64);
    }
    if (ksE == 0) {
      gL[b * 16 + r0E] = s0 + XgL[b * 16 + r0E];
      gL[b * 16 + r1E] = s1 + XgL[b * 16 + r1E];
    }
  }
  __syncthreads();
  if (tid < 128) {
    int b = tid & 31, j = tid >> 5;
    float g_i = gL[b * 16 + (j << 2) + 0];
    float g_f = gL[b * 16 + (j << 2) + 1];
    float g_g = gL[b * 16 + (j << 2) + 2];
    float g_o = gL[b * 16 + (j << 2) + 3];
    float c = (s == 0) ? 0.f : c_st[(d * 32 + b) * 512 + u0 + j];
    c = sigm(g_f) * c + sigm(g_i) * tanhf(g_g);
    float h = sigm(g_o) * tanhf(c);
    c_st[(d * 32 + b) * 512 + u0 + j] = c;
    h_enc[(((cur ^ 1) * 2 + d) * 32 + b) * 512 + u0 + j] = h;
    if (s == 127) hcat[b * 1024 + d * 512 + u0 + j] = h;  // buf 0
  }
}

// ---------------- K_cell: one decoder LSTM step (both dirs) ----------------
__global__ __launch_bounds__(NT) void k_cell(
    const int* __restrict__ tgt, const float* __restrict__ dec_emb,
    const float* __restrict__ dwih_f, const float* __restrict__ dwhh_f,
    const float* __restrict__ dbih_f, const float* __restrict__ dbhh_f,
    const float* __restrict__ dwih_r, const float* __restrict__ dwhh_r,
    const float* __restrict__ dbih_r, const float* __restrict__ dbhh_r,
    float* __restrict__ hcat, float* __restrict__ c_st,
    const unsigned long long* __restrict__ amax, int t) {
  extern __shared__ float smem[];
  const int tid = threadIdx.x;
  const int bid = blockIdx.x;
  const int d  = bid >> 7;
  const int u0 = (bid & 127) << 2;
  const int p = t & 1;

  float* xhL = smem;               // [32][XSTR]
  float* gLd = smem + 32 * XSTR;   // [32*16]

  const int rgD = tid >> 7;
  const int bpD = (tid >> 5) & 3;
  const int ksD = tid & 31;
  const int r0D = rgD * 2, r1D = r0D + 1;
  const int growD0 = (r0D & 3) * 512 + u0 + (r0D >> 2);
  const int growD1 = (r1D & 3) * 512 + u0 + (r1D >> 2);

  const float* dwih = d ? dwih_r : dwih_f;
  const float* dwhh = d ? dwhh_r : dwhh_f;
  const float* dbih = d ? dbih_r : dbih_f;
  const float* dbhh = d ? dbhh_r : dbhh_f;

  {
    int b = tid >> 5, i = tid & 31;
    int tok;
    if (t == 0) {
      tok = tgt[b * 64];
    } else {
      unsigned long long kv = amax[(t - 1) * 32 + b];
      tok = (int)(0xFFFFFFFFu - (unsigned)(kv & 0xFFFFFFFFull));
    }
    const float* xr = dec_emb + (size_t)tok * 512;
    const float* hr = hcat + (size_t)p * 32768 + b * 1024 + d * 512;
#pragma unroll
    for (int q = 0; q < 4; ++q) {
      int k = (i + 32 * q) * 4;
      float4 v = *(const float4*)(xr + k);
      int pc = k + ((k >> 5) << 2);
      *(float4*)(xhL + b * XSTR + pc) = v;
    }
#pragma unroll
    for (int q = 0; q < 4; ++q) {
      int k = (i + 32 * q) * 4;
      float4 v = *(const float4*)(hr + k);
      int c2 = 512 + k;
      int pc = c2 + ((c2 >> 5) << 2);
      *(float4*)(xhL + b * XSTR + pc) = v;
    }
  }
  float4 wA[8], wB[8];
  {
    const float* s0p = (ksD < 16) ? (dwih + (size_t)growD0 * 512 + ksD * 32)
                                  : (dwhh + (size_t)growD0 * 512 + (ksD - 16) * 32);
    const float* s1p = (ksD < 16) ? (dwih + (size_t)growD1 * 512 + ksD * 32)
                                  : (dwhh + (size_t)growD1 * 512 + (ksD - 16) * 32);
#pragma unroll
    for (int i4 = 0; i4 < 8; ++i4) {
      wA[i4] = *(const float4*)(s0p + i4 * 4);
      wB[i4] = *(const float4*)(s1p + i4 * 4);
    }
  }
  const float biasA = dbih[growD0] + dbhh[growD0];
  const float biasB = dbih[growD1] + dbhh[growD1];
  __syncthreads();
  for (int gi = 0; gi < 8; ++gi) {
    int b = bpD * 8 + gi;
    const float* hb = xhL + b * XSTR + ksD * 36;
    float4 a0 = {0, 0, 0, 0}, a1 = {0, 0, 0, 0};
#pragma unroll
    for (int i4 = 0; i4 < 8; ++i4) {
      float4 h4 = *(const float4*)(hb + i4 * 4);
      fma4(wA[i4], h4, a0);
      fma4(wB[i4], h4, a1);
    }
    float s0 = hsum4(a0), s1 = hsum4(a1);
#pragma unroll
    for (int m = 1; m <= 16; m <<= 1) {
      s0 += __shfl_xor(s0, m, 64);
      s1 += __shfl_xor(s1, m, 64);
    }
    if (ksD == 0) {
      gLd[b * 16 + r0D] = s0 + biasA;
      gLd[b * 16 + r1D] = s1 + biasB;
    }
  }
  __syncthreads();
  if (tid < 128) {
    int b = tid & 31, j = tid >> 5;
    float g_i = gLd[b * 16 + (j << 2) + 0];
    float g_f = gLd[b * 16 + (j << 2) + 1];
    float g_g = gLd[b * 16 + (j << 2) + 2];
    float g_o = gLd[b * 16 + (j << 2) + 3];
    float c = c_st[(d * 32 + b) * 512 + u0 + j];
    c = sigm(g_f) * c + sigm(g_i) * tanhf(g_g);
    float h = sigm(g_o) * tanhf(c);
    c_st[(d * 32 + b) * 512 + u0 + j] = c;
    hcat[(size_t)(p ^ 1) * 32768 + b * 1024 + d * 512 + u0 + j] = h;
  }
}

// ---------------- K_cls: classifier + argmax (v6 layout) ----------------
__global__ __launch_bounds__(NT) void k_cls(
    const float* __restrict__ cls_w, const float* __restrict__ cls_b,
    const float* __restrict__ hcat, unsigned long long* __restrict__ amax,
    float* __restrict__ out, int t) {
  extern __shared__ float smem[];
  const int tid = threadIdx.x;
  const int bid = blockIdx.x;
  const int p = t & 1;

  float* oL = smem + 32896;
  unsigned long long* amaxL = (unsigned long long*)(smem + 37504);

  {  // stage h into padded cH [32][257] float4; zero amaxL
    const float4* hr4 = (const float4*)(hcat + (size_t)(p ^ 1) * 32768);
    float4* cH4w = (float4*)smem;
#pragma unroll
    for (int q = 0; q < 8; ++q) {
      int f = tid + q * 1024;
      int b = f >> 8, k4 = f & 255;
      cH4w[b * 257 + k4] = hr4[f];
    }
    if (tid < 32) amaxL[tid] = 0ull;
  }
  __syncthreads();
  {
    const int lane = tid & 63;
    const int widu = __builtin_amdgcn_readfirstlane(tid >> 6);
    const int kc = lane & 3;
    const int bg = lane >> 2;
    const int b0 = bg * 2, b1 = b0 + 1;
    const float4* cH4 = (const float4*)smem;

    const float* wr[8];
#pragma unroll
    for (int r = 0; r < 8; ++r) {
      int lr = widu * 8 + r;
      lr = lr > 124 ? 124 : lr;
      wr[r] = cls_w + (size_t)(bid * 125 + lr) * 1024;
    }

    float acc[16];
#pragma unroll
    for (int i = 0; i < 16; ++i) acc[i] = 0.f;

    const float4* hp0 = cH4 + b0 * 257 + kc;
    const float4* hp1 = cH4 + b1 * 257 + kc;
    const int fo = kc * 4;
#pragma unroll 2
    for (int q = 0; q < 64; ++q) {
      const int ko = q * 16 + fo;
      float4 w0 = *(const float4*)(wr[0] + ko);
      float4 w1 = *(const float4*)(wr[1] + ko);
      float4 w2 = *(const float4*)(wr[2] + ko);
      float4 w3 = *(const float4*)(wr[3] + ko);
      float4 w4 = *(const float4*)(wr[4] + ko);
      float4 w5 = *(const float4*)(wr[5] + ko);
      float4 w6 = *(const float4*)(wr[6] + ko);
      float4 w7 = *(const float4*)(wr[7] + ko);
      float4 h40 = hp0[q * 4];
      float4 h41 = hp1[q * 4];
      acc[0]  = dot4(w0, h40, acc[0]);   acc[1]  = dot4(w0, h41, acc[1]);
      acc[2]  = dot4(w1, h40, acc[2]);   acc[3]  = dot4(w1, h41, acc[3]);
      acc[4]  = dot4(w2, h40, acc[4]);   acc[5]  = dot4(w2, h41, acc[5]);
      acc[6]  = dot4(w3, h40, acc[6]);   acc[7]  = dot4(w3, h41, acc[7]);
      acc[8]  = dot4(w4, h40, acc[8]);   acc[9]  = dot4(w4, h41, acc[9]);
      acc[10] = dot4(w5, h40, acc[10]);  acc[11] = dot4(w5, h41, acc[11]);
      acc[12] = dot4(w6, h40, acc[12]);  acc[13] = dot4(w6, h41, acc[13]);
      acc[14] = dot4(w7, h40, acc[14]);  acc[15] = dot4(w7, h41, acc[15]);
    }

#pragma unroll
    for (int i = 0; i < 16; ++i) {
      acc[i] += __shfl_xor(acc[i], 1, 64);
      acc[i] += __shfl_xor(acc[i], 2, 64);
    }

    float sA0, sA1, sB0, sB1;
    {
      float t0 = (kc & 1) ? acc[2]  : acc[0];
      float t1 = (kc & 1) ? acc[6]  : acc[4];
      sA0 = (kc & 2) ? t1 : t0;
      float u0v = (kc & 1) ? acc[3]  : acc[1];
      float u1v = (kc & 1) ? acc[7]  : acc[5];
      sA1 = (kc & 2) ? u1v : u0v;
      float v0v = (kc & 1) ? acc[10] : acc[8];
      float v1v = (kc & 1) ? acc[14] : acc[12];
      sB0 = (kc & 2) ? v1v : v0v;
      float w0v = (kc & 1) ? acc[11] : acc[9];
      float w1v = (kc & 1) ? acc[15] : acc[13];
      sB1 = (kc & 2) ? w1v : w0v;
    }

    const int lrA = widu * 8 + kc;
    const int lrB = lrA + 4;
    const int lrBc = lrB > 124 ? 124 : lrB;
    const int vrA = bid * 125 + lrA;
    const int vrB = bid * 125 + lrBc;
    const float cbA = cls_b[vrA];
    const float cbB = cls_b[vrB];
    const float lgA0 = sA0 + cbA, lgA1 = sA1 + cbA;
    const float lgB0 = sB0 + cbB, lgB1 = sB1 + cbB;

    oL[b0 * 130 + lrA] = lgA0;
    oL[b1 * 130 + lrA] = lgA1;
    if (lrB < 125) {
      oL[b0 * 130 + lrB] = lgB0;
      oL[b1 * 130 + lrB] = lgB1;
    }

    unsigned long long k0 = lgkey(lgA0, vrA);
    unsigned long long k1 = lgkey(lgA1, vrA);
    if (lrB < 125) {
      unsigned long long kB0 = lgkey(lgB0, vrB);
      unsigned long long kB1 = lgkey(lgB1, vrB);
      k0 = kB0 > k0 ? kB0 : k0;
      k1 = kB1 > k1 ? kB1 : k1;
    }
#pragma unroll
    for (int m = 1; m <= 2; m <<= 1) {
      unsigned long long o0 = __shfl_xor(k0, m, 64);
      unsigned long long o1 = __shfl_xor(k1, m, 64);
      k0 = o0 > k0 ? o0 : k0;
      k1 = o1 > k1 ? o1 : k1;
    }
    if (kc == 0) {
      atomicMax(&amaxL[b0], k0);
      atomicMax(&amaxL[b1], k1);
    }
  }
  __syncthreads();
#pragma unroll
  for (int it = 0; it < 4; ++it) {
    int idx = tid + it * 1024;
    int b = idx >> 7, j = idx & 127;
    if (j < 125)
      out[((size_t)b * 64 + (t + 1)) * 32000 + bid * 125 + j] = oL[b * 130 + j];
  }
  if (tid < 32) atomicMax(&amax[t * 32 + tid], amaxL[tid]);
}

extern "C" void kernel_launch(void* const* d_in, const int* in_sizes, int n_in,
                              void* d_out, int out_size, void* d_ws, size_t ws_size,
                              hipStream_t stream) {
  (void)in_sizes; (void)n_in; (void)out_size; (void)ws_size;
  const int*   src     = (const int*)d_in[0];
  const int*   tgt     = (const int*)d_in[1];
  const float* enc_emb = (const float*)d_in[2];
  const float* dec_emb = (const float*)d_in[3];
  const float* ewih_f  = (const float*)d_in[4];
  const float* ewhh_f  = (const float*)d_in[5];
  const float* ebih_f  = (const float*)d_in[6];
  const float* ebhh_f  = (const float*)d_in[7];
  const float* ewih_r  = (const float*)d_in[8];
  const float* ewhh_r  = (const float*)d_in[9];
  const float* ebih_r  = (const float*)d_in[10];
  const float* ebhh_r  = (const float*)d_in[11];
  const float* dwih_f  = (const float*)d_in[12];
  const float* dwhh_f  = (const float*)d_in[13];
  const float* dbih_f  = (const float*)d_in[14];
  const float* dbhh_f  = (const float*)d_in[15];
  const float* dwih_r  = (const float*)d_in[16];
  const float* dwhh_r  = (const float*)d_in[17];
  const float* dbih_r  = (const float*)d_in[18];
  const float* dbhh_r  = (const float*)d_in[19];
  const float* cls_w   = (const float*)d_in[20];
  const float* cls_b   = (const float*)d_in[21];

  char* ws = (char*)d_ws;
  unsigned long long* amax = (unsigned long long*)(ws + OFF_AMAX);
  float* Xg                = (float*)(ws + OFF_XG);
  float* h_enc             = (float*)(ws + OFF_HENC);
  float* hcat              = (float*)(ws + OFF_HCAT);
  float* c_st              = (float*)(ws + OFF_CST);
  float* out               = (float*)d_out;

  // reset argmax slots (monotone atomicMax needs zeros each call)
  hipMemsetAsync(d_ws, 0, OFF_XG, stream);

  hipFuncSetAttribute((const void*)k_xg,
                      hipFuncAttributeMaxDynamicSharedMemorySize, LDS_ENC);
  hipFuncSetAttribute((const void*)k_enc,
                      hipFuncAttributeMaxDynamicSharedMemorySize, LDS_ENC);
  hipFuncSetAttribute((const void*)k_cell,
                      hipFuncAttributeMaxDynamicSharedMemorySize, LDS_CELL);
  hipFuncSetAttribute((const void*)k_cls,
                      hipFuncAttributeMaxDynamicSharedMemorySize, LDS_CLS);

  hipLaunchKernelGGL(k_xg, dim3(NBLK), dim3(NT), LDS_ENC, stream,
                     src, enc_emb, ewih_f, ebih_f, ebhh_f,
                     ewih_r, ebih_r, ebhh_r, Xg, h_enc, out);

  for (int s = 0; s < 128; ++s) {
    hipLaunchKernelGGL(k_enc, dim3(NBLK), dim3(NT), LDS_ENC, stream,
                       ewhh_f, ewhh_r, Xg, h_enc, hcat, c_st, s);
  }

  for (int t = 0; t < 63; ++t) {
    hipLaunchKernelGGL(k_cell, dim3(NBLK), dim3(NT), LDS_CELL, stream,
                       tgt, dec_emb,
                       dwih_f, dwhh_f, dbih_f, dbhh_f,
                       dwih_r, dwhh_r, dbih_r, dbhh_r,
                       hcat, c_st, amax, t);
    hipLaunchKernelGGL(k_cls, dim3(NBLK), dim3(NT), LDS_CLS, stream,
                       cls_w, cls_b, hcat, amax, out, t);
  }
}